// Round 8
// baseline (519.730 us; speedup 1.0000x reference)
//
#include <hip/hip_runtime.h>

typedef unsigned short u16;
typedef __bf16 bf16x8 __attribute__((ext_vector_type(8)));
typedef float f32x4 __attribute__((ext_vector_type(4)));

#define B_ 32
#define T_ 512
#define H_ 1024
#define E_ 2048
#define S_ 128

__device__ inline u16 f2bf(float f) {
  union { float f; unsigned int u; } c; c.f = f;
  unsigned int u = c.u;
  unsigned int r = (u + 0x7FFFu + ((u >> 16) & 1u)) >> 16;
  return (u16)r;
}
__device__ inline float bf2f(u16 h) {
  union { unsigned int u; float f; } c; c.u = ((unsigned int)h) << 16; return c.f;
}
__device__ inline float silu_fast(float v) {
  return v * __builtin_amdgcn_rcpf(1.0f + __expf(-v));
}

// async 16B global->LDS DMA (width=16 => global_load_lds_dwordx4)
__device__ inline void g2lds16(const u16* g, u16* l) {
  __builtin_amdgcn_global_load_lds(
      (const __attribute__((address_space(1))) void*)g,
      (__attribute__((address_space(3))) void*)l, 16, 0, 0);
}

// ---------------- LayerNorm: one block (256 thr) per row of H=1024 -----------
__global__ __launch_bounds__(256) void ln_kernel(const float* __restrict__ x,
                                                 const float* __restrict__ lw,
                                                 const float* __restrict__ lb,
                                                 u16* __restrict__ xn) {
  int row = blockIdx.x;
  int t = threadIdx.x;
  const float4* xr = (const float4*)(x + (size_t)row * H_);
  float4 v = xr[t];
  float s = v.x + v.y + v.z + v.w;
  float ss = v.x * v.x + v.y * v.y + v.z * v.z + v.w * v.w;
  for (int off = 1; off < 64; off <<= 1) {
    s += __shfl_xor(s, off);
    ss += __shfl_xor(ss, off);
  }
  __shared__ float red[8];
  int w = t >> 6, l = t & 63;
  if (l == 0) { red[w] = s; red[4 + w] = ss; }
  __syncthreads();
  s = red[0] + red[1] + red[2] + red[3];
  ss = red[4] + red[5] + red[6] + red[7];
  float mu = s * (1.0f / H_);
  float var = ss * (1.0f / H_) - mu * mu;
  float inv = rsqrtf(var + 1e-5f);
  int i = t * 4;
  ushort4 o;
  o.x = f2bf((v.x - mu) * inv * lw[i] + lb[i]);
  o.y = f2bf((v.y - mu) * inv * lw[i + 1] + lb[i + 1]);
  o.z = f2bf((v.z - mu) * inv * lw[i + 2] + lb[i + 2]);
  o.w = f2bf((v.w - mu) * inv * lw[i + 3] + lb[i + 3]);
  *(ushort4*)(xn + (size_t)row * H_ + i) = o;
}

// ---------------- f32 -> bf16 converter (n4 = count/4) -----------------------
__global__ void cvt_kernel(const float* __restrict__ in, u16* __restrict__ out, int n4) {
  int i = blockIdx.x * 256 + threadIdx.x;
  if (i < n4) {
    float4 v = ((const float4*)in)[i];
    ushort4 o;
    o.x = f2bf(v.x); o.y = f2bf(v.y); o.z = f2bf(v.z); o.w = f2bf(v.w);
    ((ushort4*)out)[i] = o;
  }
}

// ---------------- gamma/beta + RoPE -> q,k (bf16) ----------------------------
__global__ __launch_bounds__(256) void rope_kernel(const float* __restrict__ base,
                                                   const float* __restrict__ gamma,
                                                   const float* __restrict__ beta,
                                                   u16* __restrict__ q,
                                                   u16* __restrict__ k) {
  int row = blockIdx.x * 4 + (threadIdx.x >> 6);  // b*T + t
  int s = threadIdx.x & 63;
  int t = row & (T_ - 1);
  const float* bp = base + (size_t)row * S_;
  float b1 = bp[s], b2 = bp[s + 64];
  float q1 = b1 * gamma[s] + beta[s];
  float q2 = b2 * gamma[64 + s] + beta[64 + s];
  float k1 = b1 * gamma[128 + s] + beta[128 + s];
  float k2 = b2 * gamma[192 + s] + beta[192 + s];
  float invf = (float)pow(10000.0, (double)s * (1.0 / 64.0));
  float ph = (float)t * invf;
  float sn, cs;
  sincosf(ph, &sn, &cs);
  size_t o = (size_t)row * S_;
  q[o + s]      = f2bf(q1 * cs - q2 * sn);
  q[o + 64 + s] = f2bf(q2 * cs + q1 * sn);
  k[o + s]      = f2bf(k1 * cs - k2 * sn);
  k[o + 64 + s] = f2bf(k2 * cs + k1 * sn);
}

// ---------------- 128x128-tile bf16 MFMA GEMM (legacy, verified) -------------
// Kept for: GEMM1 (K=128, small) and the 128-col `base` slice of GEMM0.
// nb0 = column offset added to blockIdx.x*128.
template <int MODE>
__global__ __launch_bounds__(256)
void gemm_bt(const u16* __restrict__ A, const u16* __restrict__ Bm,
             int K, long long sA, long long sB,
             void* __restrict__ o0, void* __restrict__ o1, void* __restrict__ o2,
             const void* __restrict__ c0, const void* __restrict__ c1, int nb0) {
  __shared__ __attribute__((aligned(16))) u16 lds[32768];
  u16* lsA = lds;
  u16* lsB = lds + 16384;

  const int z = blockIdx.z;
  const u16* Ab = A + (long long)z * sA;
  const u16* Bb = Bm + (long long)z * sB;
  const int m0 = blockIdx.y * 128;
  const int n0 = nb0 + blockIdx.x * 128;
  const int t = threadIdx.x;
  const int w = t >> 6, l = t & 63;
  const int quad = l >> 4, l16 = l & 15;
  const int wm = (w >> 1) * 64, wn = (w & 1) * 64;
  const int srow = t >> 4;
  const int gl = (t & 15) ^ ((t >> 4) & 7);
  const int dst_off = t * 8;
  const int rsw = l16 & 7;

  f32x4 zero = {0.f, 0.f, 0.f, 0.f};
  f32x4 acc[4][4];
  for (int mi = 0; mi < 4; ++mi)
    for (int ni = 0; ni < 4; ++ni) acc[mi][ni] = zero;

  const u16* gA = Ab + ((size_t)(m0 + srow) * K + gl * 8);
  const u16* gB = Bb + ((size_t)(n0 + srow) * K + gl * 8);
  const size_t rK16 = (size_t)16 * K;

  for (int k0 = 0; k0 < K; k0 += 128) {
    __syncthreads();
#pragma unroll
    for (int c = 0; c < 8; ++c)
      g2lds16(gA + k0 + c * rK16, &lsA[c * 2048 + dst_off]);
#pragma unroll
    for (int c = 0; c < 8; ++c)
      g2lds16(gB + k0 + c * rK16, &lsB[c * 2048 + dst_off]);
    __syncthreads();
#pragma unroll
    for (int j = 0; j < 4; ++j) {
      int pg = ((j * 4 + quad) ^ rsw) * 8;
      bf16x8 af[4], bfr[4];
      for (int i = 0; i < 4; ++i) {
        af[i]  = *(const bf16x8*)&lsA[(wm + i * 16 + l16) * 128 + pg];
        bfr[i] = *(const bf16x8*)&lsB[(wn + i * 16 + l16) * 128 + pg];
      }
      for (int mi = 0; mi < 4; ++mi)
        for (int ni = 0; ni < 4; ++ni)
          acc[mi][ni] = __builtin_amdgcn_mfma_f32_16x16x32_bf16(af[mi], bfr[ni], acc[mi][ni], 0, 0, 0);
    }
  }

  for (int mi = 0; mi < 4; ++mi) {
    for (int ni = 0; ni < 4; ++ni) {
      int n = n0 + wn + ni * 16 + l16;
      for (int r = 0; r < 4; ++r) {
        int m = m0 + wm + mi * 16 + quad * 4 + r;
        float a = acc[mi][ni][r];
        if constexpr (MODE == 0) {
          // base path: f32 store of silu(acc+bias), cols n >= 2E
          const float* uvb = (const float*)c0;
          ((float*)o2)[(size_t)m * S_ + (n - 2 * E_)] = silu_fast(a + uvb[n]);
        } else if constexpr (MODE == 1) {
          const float* wrel = (const float*)c0;
          float v = a * 0.08838834764831845f + wrel[n - m + 511];
          v = fmaxf(v, 0.0f);
          ((u16*)o0)[(size_t)z * (T_ * T_) + (size_t)m * T_ + n] = f2bf(v * v);
        }
      }
    }
  }
}

// ============================================================================
// 256x256-tile, BK=64, 8-wave pipelined bf16 GEMM (B^T form).
// C[m][n] = sum_k A[m][k]*B[n][k].  grid (N/256, M/256, Z), 512 thr,
// 128 KiB dynamic LDS.  (r3 K-loop -- measured best, GEMM0 = 162 us.)
//
// LDS (u16 elems): A(b,h)=b*16384+h*8192, B(b,h)=32768+b*16384+h*8192;
// each half = 128 rows x 64 cols, row-major, 128 B rows (8 x 16 B granules).
// Swizzle: phys granule p of row r holds logical p ^ (r&7); pre-swizzled
// global source, lane-linear DMA dest; conflict-free ds_read_b128 (r2).
//
// One barrier per phase: {reads(p); stage; lgkm(0); barrier; MFMA(p)} --
// every wave's reads drain BEFORE it arrives at the barrier, so the release
// globally publishes staged tiles and dead-region staging is race-free.
// Staging per K-tile kt (buf b=kt&1): ph0 A1(kt+1); ph1 B0(kt+2); ph2
// B1(kt+2); ph3 A0(kt+2) + vmcnt(6). Tail tiles use vmcnt(0).
//
// r8: epilogues de-amplified. r7 counters: WRITE_SIZE 161 MB vs ~72 ideal --
// quad-scattered scalar bf16 stores (32 B per 4-KB-strided row) are
// half-sector writes. Fix: repack the 256x256 bf16 tile through LDS
// (row-major + granule-XOR swizzle) and store contiguous 512 B rows via
// dwordx4 (u path), and for MODE 2 do wide u-load * acc -> wide store.
// ============================================================================
#define PH_SYNC()                                        \
  asm volatile("s_waitcnt lgkmcnt(0)" ::: "memory");     \
  __builtin_amdgcn_sched_barrier(0);                     \
  __builtin_amdgcn_s_barrier();                          \
  __builtin_amdgcn_sched_barrier(0);                     \
  __builtin_amdgcn_s_setprio(1);

#define PH_END()                                         \
  __builtin_amdgcn_s_setprio(0);

#define MM2(mA, mB)                                                                                       \
  _Pragma("unroll")                                                                                       \
  for (int ni = 0; ni < 4; ++ni) {                                                                        \
    acc[mA][ni] = __builtin_amdgcn_mfma_f32_16x16x32_bf16(af[mA][0], bfr[ni][0], acc[mA][ni], 0, 0, 0);   \
    acc[mB][ni] = __builtin_amdgcn_mfma_f32_16x16x32_bf16(af[mB][0], bfr[ni][0], acc[mB][ni], 0, 0, 0);   \
  }                                                                                                       \
  _Pragma("unroll")                                                                                       \
  for (int ni = 0; ni < 4; ++ni) {                                                                        \
    acc[mA][ni] = __builtin_amdgcn_mfma_f32_16x16x32_bf16(af[mA][1], bfr[ni][1], acc[mA][ni], 0, 0, 0);   \
    acc[mB][ni] = __builtin_amdgcn_mfma_f32_16x16x32_bf16(af[mB][1], bfr[ni][1], acc[mB][ni], 0, 0, 0);   \
  }

template <int MODE, bool XSWZ>
__global__ __launch_bounds__(512, 2)
void gemm256(const u16* __restrict__ A, const u16* __restrict__ Bm,
             int K, long long sA, long long sB,
             void* __restrict__ o0, void* __restrict__ o1,
             const void* __restrict__ c0, const void* __restrict__ c1) {
  extern __shared__ u16 lds[];

  int bx = blockIdx.x, by = blockIdx.y;
  if constexpr (XSWZ) {
    // bijective XCD swizzle (nwg % 8 == 0 for all our launches)
    int gx = gridDim.x;
    int nwg = gx * gridDim.y;
    int hh = by * gx + bx;
    int cpx = nwg >> 3;
    int lid = (hh & 7) * cpx + (hh >> 3);
    bx = lid % gx; by = lid / gx;
  }
  const int z = blockIdx.z;
  const u16* Ab = A + (long long)z * sA;
  const u16* Bb = Bm + (long long)z * sB;
  const int m0 = by * 256;
  const int n0 = bx * 256;
  const int t = threadIdx.x;
  const int w = t >> 6, ln = t & 63;
  const int quad = ln >> 4, l16 = ln & 15;
  const int wm = w >> 2, wn = w & 3;  // 2 x 4 wave grid; per-wave out 128x64

  const int nkt = K >> 6;

  // staging: thread t -> row (t>>3) of a 64-row slab; source granule
  // (t&7)^((t>>3)&7) (inverse swizzle); LDS dest lane-linear t*16B.
  const int goff = ((t & 7) ^ ((t >> 3) & 7)) * 8;
  const u16* gA = Ab + (size_t)(m0 + (t >> 3)) * K + goff;
  const u16* gB = Bb + (size_t)(n0 + (t >> 3)) * K + goff;
  u16* ldst = lds + t * 8;
  const size_t rK64 = (size_t)64 * K;
  const size_t rK128 = (size_t)128 * K;

  auto SA = [&](int b, int h, int kt) {
    const u16* g = gA + h * rK128 + (size_t)kt * 64;
    u16* d = ldst + b * 16384 + h * 8192;
    g2lds16(g, d);
    g2lds16(g + rK64, d + 4096);
  };
  auto SB = [&](int b, int h, int kt) {
    const u16* g = gB + h * rK128 + (size_t)kt * 64;
    u16* d = ldst + 32768 + b * 16384 + h * 8192;
    g2lds16(g, d);
    g2lds16(g + rK64, d + 4096);
  };

  f32x4 zero = {0.f, 0.f, 0.f, 0.f};
  f32x4 acc[8][4];
#pragma unroll
  for (int mi = 0; mi < 8; ++mi)
#pragma unroll
    for (int ni = 0; ni < 4; ++ni) acc[mi][ni] = zero;

  // -------- prologue: kt0 (4 halves) + kt1 (B0,B1,A0) -> vmcnt(6) ------------
  SA(0, 0, 0); SA(0, 1, 0); SB(0, 0, 0); SB(0, 1, 0);
  if (nkt > 1) {
    SB(1, 0, 1); SB(1, 1, 1); SA(1, 0, 1);
    asm volatile("s_waitcnt vmcnt(6)" ::: "memory");
  } else {
    asm volatile("s_waitcnt vmcnt(0)" ::: "memory");
  }
  __builtin_amdgcn_s_barrier();

  // fragment read bases (element offsets into lds)
  const u16* lA0 = lds + wm * 8192 + l16 * 64;
  const u16* lB0 = lds + 32768 + (wn >> 1) * 8192 + ((wn & 1) * 64 + l16) * 64;
  const int pg0 = (quad ^ (l16 & 7)) * 8;
  const int pg1 = ((4 + quad) ^ (l16 & 7)) * 8;

  bf16x8 bfr[4][2];
  bf16x8 af[8][2];

  for (int kt = 0; kt < nkt; ++kt) {
    const int b = kt & 1;
    const u16* lA = lA0 + b * 16384;
    const u16* lB = lB0 + b * 16384;
    const bool s2 = (kt + 2 < nkt);

    // ---- phase 0: B(8) + A mi0-1(4) reads | stage kt+1.A1
#pragma unroll
    for (int ni = 0; ni < 4; ++ni) {
      bfr[ni][0] = *(const bf16x8*)&lB[ni * 1024 + pg0];
      bfr[ni][1] = *(const bf16x8*)&lB[ni * 1024 + pg1];
    }
#pragma unroll
    for (int mi = 0; mi < 2; ++mi) {
      af[mi][0] = *(const bf16x8*)&lA[mi * 1024 + pg0];
      af[mi][1] = *(const bf16x8*)&lA[mi * 1024 + pg1];
    }
    if (kt + 1 < nkt) SA(b ^ 1, 1, kt + 1);
    PH_SYNC();
    MM2(0, 1);
    PH_END();

    // ---- phase 1: A mi2-5(8) reads | stage kt+2.B0
#pragma unroll
    for (int mi = 2; mi < 6; ++mi) {
      af[mi][0] = *(const bf16x8*)&lA[mi * 1024 + pg0];
      af[mi][1] = *(const bf16x8*)&lA[mi * 1024 + pg1];
    }
    if (s2) SB(b, 0, kt + 2);
    PH_SYNC();
    MM2(2, 3);
    PH_END();

    // ---- phase 2: A mi6-7(4) reads | stage kt+2.B1
#pragma unroll
    for (int mi = 6; mi < 8; ++mi) {
      af[mi][0] = *(const bf16x8*)&lA[mi * 1024 + pg0];
      af[mi][1] = *(const bf16x8*)&lA[mi * 1024 + pg1];
    }
    if (s2) SB(b, 1, kt + 2);
    PH_SYNC();
    MM2(4, 5);
    PH_END();

    // ---- phase 3: stage kt+2.A0 | counted vmcnt (kt+1 fully staged)
    if (s2) {
      SA(b, 0, kt + 2);
      asm volatile("s_waitcnt vmcnt(6)" ::: "memory");
    } else {
      asm volatile("s_waitcnt vmcnt(0)" ::: "memory");
    }
    __builtin_amdgcn_sched_barrier(0);
    __builtin_amdgcn_s_barrier();
    __builtin_amdgcn_sched_barrier(0);
    __builtin_amdgcn_s_setprio(1);
    MM2(6, 7);
    PH_END();
  }

  // -------- epilogue (C/D layout: col = l16, row = quad*4 + r) ---------------
  // LDS is reusable: all K-loop ds_reads lgkm-drained before the last barrier.
  if constexpr (MODE == 0) {
    const float* uvb = (const float*)c0;
    if (n0 < E_) {
      // ---- u path: silu -> LDS repack (row-major, granule-XOR swizzle) ->
      //      contiguous 512 B/row dwordx4 stores (r8: kills 2.2x write ampl.)
#pragma unroll
      for (int ni = 0; ni < 4; ++ni) {
        int nl = wn * 64 + ni * 16 + l16;
        float bias = uvb[n0 + nl];
        int g = nl >> 3, o = nl & 7;
#pragma unroll
        for (int mi = 0; mi < 8; ++mi)
#pragma unroll
          for (int r = 0; r < 4; ++r) {
            int ml = wm * 128 + mi * 16 + quad * 4 + r;
            lds[ml * 256 + ((g ^ (ml & 7)) << 3) + o] =
                f2bf(silu_fast(acc[mi][ni][r] + bias));
          }
      }
      __syncthreads();
      u16* o0p = (u16*)o0;
#pragma unroll
      for (int cc = 0; cc < 16; ++cc) {
        int gidx = cc * 512 + t;       // 0..8191 granules (256 rows x 32)
        int row = gidx >> 5, gc = gidx & 31;
        uint4 val = *(const uint4*)&lds[row * 256 + ((gc ^ (row & 7)) << 3)];
        *(uint4*)&o0p[(size_t)(m0 + row) * E_ + n0 + gc * 8] = val;
      }
    } else {
      // ---- v path: silu, then full 256x256 transpose through LDS -> vt[b][e][t]
      const int bb = m0 >> 9;
      const int tt0 = m0 & (T_ - 1);
      const int nv0 = n0 - E_;
#pragma unroll
      for (int ni = 0; ni < 4; ++ni) {
        int nl = wn * 64 + ni * 16 + l16;
        float bias = uvb[n0 + nl];
#pragma unroll
        for (int mi = 0; mi < 8; ++mi)
#pragma unroll
          for (int r = 0; r < 4; ++r) {
            int ml = wm * 128 + mi * 16 + quad * 4 + r;
            u16 sv = f2bf(silu_fast(acc[mi][ni][r] + bias));
            int g = ml >> 3, o = ml & 7;
            lds[nl * 256 + ((g ^ (nl & 7)) << 3) + o] = sv;
          }
      }
      __syncthreads();
      int row = t >> 1;  // e-row 0..255, two threads per row
      u16* o1p = (u16*)o1;
      size_t gbase = ((size_t)bb * E_ + nv0 + row) * T_ + tt0;
#pragma unroll
      for (int cc = 0; cc < 16; ++cc) {
        int c = (t & 1) * 16 + cc;
        int gs = c ^ (row & 7);
        uint4 val = *(const uint4*)&lds[row * 256 + gs * 8];
        *(uint4*)&o1p[gbase + c * 8] = val;
      }
    }
  } else if constexpr (MODE == 2) {
    // attn = (kernel @ v) * u, IN PLACE over u. r8: LDS repack of bf16(acc),
    // then wide u-load * acc -> wide store (was scalar 2B RMW both ways).
#pragma unroll
    for (int ni = 0; ni < 4; ++ni) {
      int nl = wn * 64 + ni * 16 + l16;
      int g = nl >> 3, o = nl & 7;
#pragma unroll
      for (int mi = 0; mi < 8; ++mi)
#pragma unroll
        for (int r = 0; r < 4; ++r) {
          int ml = wm * 128 + mi * 16 + quad * 4 + r;
          lds[ml * 256 + ((g ^ (ml & 7)) << 3) + o] = f2bf(acc[mi][ni][r]);
        }
    }
    __syncthreads();
    const u16* uu = (const u16*)c0;
    u16* o0p = (u16*)o0;
#pragma unroll
    for (int cc = 0; cc < 16; ++cc) {
      int gidx = cc * 512 + t;
      int row = gidx >> 5, gc = gidx & 31;
      union { uint4 v; u16 h[8]; } av, uv_, rv;
      av.v = *(const uint4*)&lds[row * 256 + ((gc ^ (row & 7)) << 3)];
      size_t gi = ((size_t)z * T_ + m0 + row) * E_ + n0 + gc * 8;
      uv_.v = *(const uint4*)&uu[gi];
#pragma unroll
      for (int k = 0; k < 8; ++k)
        rv.h[k] = f2bf(bf2f(av.h[k]) * bf2f(uv_.h[k]));
      *(uint4*)&o0p[gi] = rv.v;
    }
  } else {
    // MODE 3: out = acc + o_b + shortcut -> f32 (64 B/quad sectors; fine)
    const float* ob = (const float*)c0;
    const float* xs = (const float*)c1;
#pragma unroll
    for (int ni = 0; ni < 4; ++ni) {
      int n = n0 + wn * 64 + ni * 16 + l16;
      float bias = ob[n];
#pragma unroll
      for (int mi = 0; mi < 8; ++mi)
#pragma unroll
        for (int r = 0; r < 4; ++r) {
          int m = m0 + wm * 128 + mi * 16 + quad * 4 + r;
          size_t gi = (size_t)m * H_ + n;
          ((float*)o0)[gi] = acc[mi][ni][r] + bias + xs[gi];
        }
    }
  }
}

extern "C" void kernel_launch(void* const* d_in, const int* in_sizes, int n_in,
                              void* d_out, int out_size, void* d_ws, size_t ws_size,
                              hipStream_t stream) {
  const float* x     = (const float*)d_in[0];
  const float* ln_w  = (const float*)d_in[1];
  const float* ln_b  = (const float*)d_in[2];
  const float* uv_w  = (const float*)d_in[3];
  const float* uv_b  = (const float*)d_in[4];
  const float* gamma = (const float*)d_in[5];
  const float* beta  = (const float*)d_in[6];
  const float* wrel  = (const float*)d_in[7];
  const float* o_w   = (const float*)d_in[8];
  const float* o_b   = (const float*)d_in[9];

  char* ws = (char*)d_ws;
  u16*   xn   = (u16*)(ws);
  u16*   qb   = (u16*)(ws);
  u16*   kb   = (u16*)(ws + 4194304);
  u16*   km   = (u16*)(ws + 8388608);
  u16*   uvwb = (u16*)(ws + 33554432);
  u16*   owb  = (u16*)(ws + 42205184);
  u16*   u    = (u16*)(ws + 46399488);
  u16*   vt   = (u16*)(ws + 113508352);
  float* base = (float*)(ws + 180617216);
  u16*   attn = u;

  // one-time: allow 128 KiB dynamic LDS for the 256^2 kernels.
  static int ldsset = -1;
  if (ldsset < 0) {
    auto* k0 = gemm256<0, true>;
    auto* k2 = gemm256<2, false>;
    auto* k3 = gemm256<3, true>;
    hipFuncSetAttribute((const void*)k0, hipFuncAttributeMaxDynamicSharedMemorySize, 131072);
    hipFuncSetAttribute((const void*)k2, hipFuncAttributeMaxDynamicSharedMemorySize, 131072);
    hipFuncSetAttribute((const void*)k3, hipFuncAttributeMaxDynamicSharedMemorySize, 131072);
    ldsset = 1;
  }

  // 1. LayerNorm -> bf16
  ln_kernel<<<16384, 256, 0, stream>>>(x, ln_w, ln_b, xn);
  // 2. weight conversions
  cvt_kernel<<<4224, 256, 0, stream>>>(uv_w, uvwb, 4224 * 1024 / 4);
  cvt_kernel<<<2048, 256, 0, stream>>>(o_w, owb, 1024 * 2048 / 4);

  // 3a. uv GEMM, u+v columns (N=4096): 256^2 kernel (r3 grid: 16x64)
  gemm256<0, true><<<dim3(16, 64, 1), 512, 131072, stream>>>(
      xn, uvwb, 1024, 0, 0, u, vt, uv_b, nullptr);
  // 3b. base columns (4096..4223): legacy kernel, n-offset 4096 -> f32 base
  gemm_bt<0><<<dim3(1, 128, 1), 256, 0, stream>>>(
      xn, uvwb, 1024, 0, 0, nullptr, nullptr, base, uv_b, nullptr, 4096);
  // 4. gamma/beta + RoPE -> q,k (xn dead; qb/kb alias it)
  rope_kernel<<<4096, 256, 0, stream>>>(base, gamma, beta, qb, kb);
  // 5. qk per batch (K=128, tiny): legacy kernel
  gemm_bt<1><<<dim3(4, 4, 32), 256, 0, stream>>>(
      qb, kb, 128, 65536, 65536, km, nullptr, nullptr, wrel, nullptr, 0);
  // 6. kernel @ v per batch, * u in place
  gemm256<2, false><<<dim3(8, 2, 32), 512, 131072, stream>>>(
      km, vt, 512, 262144, 1048576, attn, nullptr, u, nullptr);
  // 7. final: + o_b + shortcut
  gemm256<3, true><<<dim3(4, 64, 1), 512, 131072, stream>>>(
      attn, owb, 2048, 0, 0, d_out, nullptr, o_b, x);
}

// Round 10
// 475.545 us; speedup vs baseline: 1.0929x; 1.0929x over previous
//
#include <hip/hip_runtime.h>

typedef unsigned short u16;
typedef __bf16 bf16x8 __attribute__((ext_vector_type(8)));
typedef float f32x4 __attribute__((ext_vector_type(4)));

#define B_ 32
#define T_ 512
#define H_ 1024
#define E_ 2048
#define S_ 128

__device__ inline u16 f2bf(float f) {
  union { float f; unsigned int u; } c; c.f = f;
  unsigned int u = c.u;
  unsigned int r = (u + 0x7FFFu + ((u >> 16) & 1u)) >> 16;
  return (u16)r;
}
__device__ inline float bf2f(u16 h) {
  union { unsigned int u; float f; } c; c.u = ((unsigned int)h) << 16; return c.f;
}
__device__ inline float silu_fast(float v) {
  return v * __builtin_amdgcn_rcpf(1.0f + __expf(-v));
}

// async 16B global->LDS DMA (width=16 => global_load_lds_dwordx4)
__device__ inline void g2lds16(const u16* g, u16* l) {
  __builtin_amdgcn_global_load_lds(
      (const __attribute__((address_space(1))) void*)g,
      (__attribute__((address_space(3))) void*)l, 16, 0, 0);
}

// ---------------- LayerNorm: one block (256 thr) per row of H=1024 -----------
__global__ __launch_bounds__(256) void ln_kernel(const float* __restrict__ x,
                                                 const float* __restrict__ lw,
                                                 const float* __restrict__ lb,
                                                 u16* __restrict__ xn) {
  int row = blockIdx.x;
  int t = threadIdx.x;
  const float4* xr = (const float4*)(x + (size_t)row * H_);
  float4 v = xr[t];
  float s = v.x + v.y + v.z + v.w;
  float ss = v.x * v.x + v.y * v.y + v.z * v.z + v.w * v.w;
  for (int off = 1; off < 64; off <<= 1) {
    s += __shfl_xor(s, off);
    ss += __shfl_xor(ss, off);
  }
  __shared__ float red[8];
  int w = t >> 6, l = t & 63;
  if (l == 0) { red[w] = s; red[4 + w] = ss; }
  __syncthreads();
  s = red[0] + red[1] + red[2] + red[3];
  ss = red[4] + red[5] + red[6] + red[7];
  float mu = s * (1.0f / H_);
  float var = ss * (1.0f / H_) - mu * mu;
  float inv = rsqrtf(var + 1e-5f);
  int i = t * 4;
  ushort4 o;
  o.x = f2bf((v.x - mu) * inv * lw[i] + lb[i]);
  o.y = f2bf((v.y - mu) * inv * lw[i + 1] + lb[i + 1]);
  o.z = f2bf((v.z - mu) * inv * lw[i + 2] + lb[i + 2]);
  o.w = f2bf((v.w - mu) * inv * lw[i + 3] + lb[i + 3]);
  *(ushort4*)(xn + (size_t)row * H_ + i) = o;
}

// ---------------- f32 -> bf16 converter (n4 = count/4) -----------------------
__global__ void cvt_kernel(const float* __restrict__ in, u16* __restrict__ out, int n4) {
  int i = blockIdx.x * 256 + threadIdx.x;
  if (i < n4) {
    float4 v = ((const float4*)in)[i];
    ushort4 o;
    o.x = f2bf(v.x); o.y = f2bf(v.y); o.z = f2bf(v.z); o.w = f2bf(v.w);
    ((ushort4*)out)[i] = o;
  }
}

// ---------------- gamma/beta + RoPE -> q,k (bf16) ----------------------------
__global__ __launch_bounds__(256) void rope_kernel(const float* __restrict__ base,
                                                   const float* __restrict__ gamma,
                                                   const float* __restrict__ beta,
                                                   u16* __restrict__ q,
                                                   u16* __restrict__ k) {
  int row = blockIdx.x * 4 + (threadIdx.x >> 6);  // b*T + t
  int s = threadIdx.x & 63;
  int t = row & (T_ - 1);
  const float* bp = base + (size_t)row * S_;
  float b1 = bp[s], b2 = bp[s + 64];
  float q1 = b1 * gamma[s] + beta[s];
  float q2 = b2 * gamma[64 + s] + beta[64 + s];
  float k1 = b1 * gamma[128 + s] + beta[128 + s];
  float k2 = b2 * gamma[192 + s] + beta[192 + s];
  float invf = (float)pow(10000.0, (double)s * (1.0 / 64.0));
  float ph = (float)t * invf;
  float sn, cs;
  sincosf(ph, &sn, &cs);
  size_t o = (size_t)row * S_;
  q[o + s]      = f2bf(q1 * cs - q2 * sn);
  q[o + 64 + s] = f2bf(q2 * cs + q1 * sn);
  k[o + s]      = f2bf(k1 * cs - k2 * sn);
  k[o + 64 + s] = f2bf(k2 * cs + k1 * sn);
}

// ---------------- 128x128-tile bf16 MFMA GEMM (legacy, verified) -------------
// Kept for: GEMM1 (K=128, small) and the 128-col `base` slice of GEMM0.
// nb0 = column offset added to blockIdx.x*128.
template <int MODE>
__global__ __launch_bounds__(256)
void gemm_bt(const u16* __restrict__ A, const u16* __restrict__ Bm,
             int K, long long sA, long long sB,
             void* __restrict__ o0, void* __restrict__ o1, void* __restrict__ o2,
             const void* __restrict__ c0, const void* __restrict__ c1, int nb0) {
  __shared__ __attribute__((aligned(16))) u16 lds[32768];
  u16* lsA = lds;
  u16* lsB = lds + 16384;

  const int z = blockIdx.z;
  const u16* Ab = A + (long long)z * sA;
  const u16* Bb = Bm + (long long)z * sB;
  const int m0 = blockIdx.y * 128;
  const int n0 = nb0 + blockIdx.x * 128;
  const int t = threadIdx.x;
  const int w = t >> 6, l = t & 63;
  const int quad = l >> 4, l16 = l & 15;
  const int wm = (w >> 1) * 64, wn = (w & 1) * 64;
  const int srow = t >> 4;
  const int gl = (t & 15) ^ ((t >> 4) & 7);
  const int dst_off = t * 8;
  const int rsw = l16 & 7;

  f32x4 zero = {0.f, 0.f, 0.f, 0.f};
  f32x4 acc[4][4];
  for (int mi = 0; mi < 4; ++mi)
    for (int ni = 0; ni < 4; ++ni) acc[mi][ni] = zero;

  const u16* gA = Ab + ((size_t)(m0 + srow) * K + gl * 8);
  const u16* gB = Bb + ((size_t)(n0 + srow) * K + gl * 8);
  const size_t rK16 = (size_t)16 * K;

  for (int k0 = 0; k0 < K; k0 += 128) {
    __syncthreads();
#pragma unroll
    for (int c = 0; c < 8; ++c)
      g2lds16(gA + k0 + c * rK16, &lsA[c * 2048 + dst_off]);
#pragma unroll
    for (int c = 0; c < 8; ++c)
      g2lds16(gB + k0 + c * rK16, &lsB[c * 2048 + dst_off]);
    __syncthreads();
#pragma unroll
    for (int j = 0; j < 4; ++j) {
      int pg = ((j * 4 + quad) ^ rsw) * 8;
      bf16x8 af[4], bfr[4];
      for (int i = 0; i < 4; ++i) {
        af[i]  = *(const bf16x8*)&lsA[(wm + i * 16 + l16) * 128 + pg];
        bfr[i] = *(const bf16x8*)&lsB[(wn + i * 16 + l16) * 128 + pg];
      }
      for (int mi = 0; mi < 4; ++mi)
        for (int ni = 0; ni < 4; ++ni)
          acc[mi][ni] = __builtin_amdgcn_mfma_f32_16x16x32_bf16(af[mi], bfr[ni], acc[mi][ni], 0, 0, 0);
    }
  }

  for (int mi = 0; mi < 4; ++mi) {
    for (int ni = 0; ni < 4; ++ni) {
      int n = n0 + wn + ni * 16 + l16;
      for (int r = 0; r < 4; ++r) {
        int m = m0 + wm + mi * 16 + quad * 4 + r;
        float a = acc[mi][ni][r];
        if constexpr (MODE == 0) {
          // base path: f32 store of silu(acc+bias), cols n >= 2E
          const float* uvb = (const float*)c0;
          ((float*)o2)[(size_t)m * S_ + (n - 2 * E_)] = silu_fast(a + uvb[n]);
        } else if constexpr (MODE == 1) {
          const float* wrel = (const float*)c0;
          float v = a * 0.08838834764831845f + wrel[n - m + 511];
          v = fmaxf(v, 0.0f);
          ((u16*)o0)[(size_t)z * (T_ * T_) + (size_t)m * T_ + n] = f2bf(v * v);
        }
      }
    }
  }
}

// ============================================================================
// 256x256-tile, BK=64, 8-wave pipelined bf16 GEMM (B^T form).
// C[m][n] = sum_k A[m][k]*B[n][k].  grid (N/256, M/256, Z), 512 thr,
// 128 KiB dynamic LDS.
//
// LDS (u16 elems): A(b,h)=b*16384+h*8192, B(b,h)=32768+b*16384+h*8192;
// each half = 128 rows x 64 cols, row-major, 128 B rows (8 x 16 B granules).
// Swizzle: phys granule p of row r holds logical p ^ (r&7); pre-swizzled
// global source, lane-linear DMA dest; conflict-free ds_read_b128 (r2).
//
// r10 K-loop (r9 raced; invariant restored): STAGE INTO A REGION ONLY AFTER
// A BARRIER PROVING ALL WAVES' READS OF IT DRAINED. With 2 buffers and one
// barrier per tile, max prefetch depth = 1 tile: after barrier(j-1), buffer
// b^1 (tile j-1's) is dead for ALL waves (each wave's lgkm(0) preceded its
// barrier arrival). Window j (buf b=j&1), between barrier(j-1) and barrier(j):
//   X0: read h0(j) [12 ds_read, k-half pg0]
//       stage ALL of tile j+1 -> buf b^1 [8 DMA]      (region dead: proof above)
//       MFMA h1(j-1) [32, register-resident -- overlaps in-flight reads]
//       lgkm(0); sched_barrier
//   X1: read h1(j) [12 ds_read, k-half pg1]
//       MFMA h0(j) [32 -- overlaps the h1 reads]
//       lgkm(0); vmcnt(0) [drains tile j+1's 8 loads, issued ~2 phases ago
//       => latency already covered; near-free]; s_barrier
// Trailing MFMA h1(nkt-1) after the loop. Every MFMA cluster issues with 12
// ds_reads in flight -> LDS pipe (2800 cyc/tile) and matrix pipe (2060)
// overlap instead of serializing (r3-r8: lockstep, MfmaUtil pinned 33-37%).
//
// r8 epilogues kept: LDS repack -> contiguous dwordx4 stores (u path, MODE2)
// killed the 2.2x write amplification (WRITE 161->133 MB, FETCH -50 MB).
// ============================================================================
#define MMH(h)                                                                                            \
  __builtin_amdgcn_s_setprio(1);                                                                          \
  _Pragma("unroll")                                                                                       \
  for (int ni = 0; ni < 4; ++ni)                                                                          \
    _Pragma("unroll")                                                                                     \
    for (int mi = 0; mi < 8; ++mi)                                                                        \
      acc[mi][ni] = __builtin_amdgcn_mfma_f32_16x16x32_bf16(af[mi][h], bfr[ni][h], acc[mi][ni], 0, 0, 0); \
  __builtin_amdgcn_s_setprio(0);

template <int MODE, bool XSWZ>
__global__ __launch_bounds__(512, 2)
void gemm256(const u16* __restrict__ A, const u16* __restrict__ Bm,
             int K, long long sA, long long sB,
             void* __restrict__ o0, void* __restrict__ o1,
             const void* __restrict__ c0, const void* __restrict__ c1) {
  extern __shared__ u16 lds[];

  int bx = blockIdx.x, by = blockIdx.y;
  if constexpr (XSWZ) {
    // bijective XCD swizzle (nwg % 8 == 0 for all our launches)
    int gx = gridDim.x;
    int nwg = gx * gridDim.y;
    int hh = by * gx + bx;
    int cpx = nwg >> 3;
    int lid = (hh & 7) * cpx + (hh >> 3);
    bx = lid % gx; by = lid / gx;
  }
  const int z = blockIdx.z;
  const u16* Ab = A + (long long)z * sA;
  const u16* Bb = Bm + (long long)z * sB;
  const int m0 = by * 256;
  const int n0 = bx * 256;
  const int t = threadIdx.x;
  const int w = t >> 6, ln = t & 63;
  const int quad = ln >> 4, l16 = ln & 15;
  const int wm = w >> 2, wn = w & 3;  // 2 x 4 wave grid; per-wave out 128x64

  const int nkt = K >> 6;

  // staging: thread t -> row (t>>3) of a 64-row slab; source granule
  // (t&7)^((t>>3)&7) (inverse swizzle); LDS dest lane-linear t*16B.
  const int goff = ((t & 7) ^ ((t >> 3) & 7)) * 8;
  const u16* gA = Ab + (size_t)(m0 + (t >> 3)) * K + goff;
  const u16* gB = Bb + (size_t)(n0 + (t >> 3)) * K + goff;
  u16* ldst = lds + t * 8;
  const size_t rK64 = (size_t)64 * K;
  const size_t rK128 = (size_t)128 * K;

  auto SA = [&](int b, int h, int kt) {
    const u16* g = gA + h * rK128 + (size_t)kt * 64;
    u16* d = ldst + b * 16384 + h * 8192;
    g2lds16(g, d);
    g2lds16(g + rK64, d + 4096);
  };
  auto SB = [&](int b, int h, int kt) {
    const u16* g = gB + h * rK128 + (size_t)kt * 64;
    u16* d = ldst + 32768 + b * 16384 + h * 8192;
    g2lds16(g, d);
    g2lds16(g + rK64, d + 4096);
  };

  f32x4 zero = {0.f, 0.f, 0.f, 0.f};
  f32x4 acc[8][4];
#pragma unroll
  for (int mi = 0; mi < 8; ++mi)
#pragma unroll
    for (int ni = 0; ni < 4; ++ni) acc[mi][ni] = zero;

  // -------- prologue: stage tile 0, publish --------------------------------
  SA(0, 0, 0); SA(0, 1, 0); SB(0, 0, 0); SB(0, 1, 0);
  asm volatile("s_waitcnt vmcnt(0)" ::: "memory");
  __builtin_amdgcn_s_barrier();

  // fragment read bases (element offsets into lds)
  const u16* lA0 = lds + wm * 8192 + l16 * 64;
  const u16* lB0 = lds + 32768 + (wn >> 1) * 8192 + ((wn & 1) * 64 + l16) * 64;
  const int pg0 = (quad ^ (l16 & 7)) * 8;
  const int pg1 = ((4 + quad) ^ (l16 & 7)) * 8;

  bf16x8 bfr[4][2];
  bf16x8 af[8][2];

  for (int kt = 0; kt < nkt; ++kt) {
    const int b = kt & 1;
    const u16* lA = lA0 + b * 16384;
    const u16* lB = lB0 + b * 16384;

    // ---- X0: half-0 reads | stage ALL of tile kt+1 -> buf b^1 (dead region)
    //          | MFMA h1(kt-1) overlaps the in-flight reads
#pragma unroll
    for (int ni = 0; ni < 4; ++ni)
      bfr[ni][0] = *(const bf16x8*)&lB[ni * 1024 + pg0];
#pragma unroll
    for (int mi = 0; mi < 8; ++mi)
      af[mi][0] = *(const bf16x8*)&lA[mi * 1024 + pg0];
    if (kt + 1 < nkt) {
      SA(b ^ 1, 0, kt + 1); SA(b ^ 1, 1, kt + 1);
      SB(b ^ 1, 0, kt + 1); SB(b ^ 1, 1, kt + 1);
    }
    if (kt > 0) { MMH(1); }
    asm volatile("s_waitcnt lgkmcnt(0)" ::: "memory");
    __builtin_amdgcn_sched_barrier(0);

    // ---- X1: half-1 reads | MFMA h0(kt) overlaps them
#pragma unroll
    for (int ni = 0; ni < 4; ++ni)
      bfr[ni][1] = *(const bf16x8*)&lB[ni * 1024 + pg1];
#pragma unroll
    for (int mi = 0; mi < 8; ++mi)
      af[mi][1] = *(const bf16x8*)&lA[mi * 1024 + pg1];
    MMH(0);
    asm volatile("s_waitcnt lgkmcnt(0)" ::: "memory");
    asm volatile("s_waitcnt vmcnt(0)" ::: "memory");
    __builtin_amdgcn_sched_barrier(0);
    __builtin_amdgcn_s_barrier();
    __builtin_amdgcn_sched_barrier(0);
  }
  // trailing half-1 MFMA of tile nkt-1
  MMH(1);

  // -------- epilogue (C/D layout: col = l16, row = quad*4 + r) ---------------
  // LDS is reusable: all K-loop ds_reads lgkm-drained before the last barrier.
  if constexpr (MODE == 0) {
    const float* uvb = (const float*)c0;
    if (n0 < E_) {
      // ---- u path: silu -> LDS repack (row-major, granule-XOR swizzle) ->
      //      contiguous 512 B/row dwordx4 stores
#pragma unroll
      for (int ni = 0; ni < 4; ++ni) {
        int nl = wn * 64 + ni * 16 + l16;
        float bias = uvb[n0 + nl];
        int g = nl >> 3, o = nl & 7;
#pragma unroll
        for (int mi = 0; mi < 8; ++mi)
#pragma unroll
          for (int r = 0; r < 4; ++r) {
            int ml = wm * 128 + mi * 16 + quad * 4 + r;
            lds[ml * 256 + ((g ^ (ml & 7)) << 3) + o] =
                f2bf(silu_fast(acc[mi][ni][r] + bias));
          }
      }
      __syncthreads();
      u16* o0p = (u16*)o0;
#pragma unroll
      for (int cc = 0; cc < 16; ++cc) {
        int gidx = cc * 512 + t;       // 0..8191 granules (256 rows x 32)
        int row = gidx >> 5, gc = gidx & 31;
        uint4 val = *(const uint4*)&lds[row * 256 + ((gc ^ (row & 7)) << 3)];
        *(uint4*)&o0p[(size_t)(m0 + row) * E_ + n0 + gc * 8] = val;
      }
    } else {
      // ---- v path: silu, then full 256x256 transpose through LDS -> vt[b][e][t]
      const int bb = m0 >> 9;
      const int tt0 = m0 & (T_ - 1);
      const int nv0 = n0 - E_;
#pragma unroll
      for (int ni = 0; ni < 4; ++ni) {
        int nl = wn * 64 + ni * 16 + l16;
        float bias = uvb[n0 + nl];
#pragma unroll
        for (int mi = 0; mi < 8; ++mi)
#pragma unroll
          for (int r = 0; r < 4; ++r) {
            int ml = wm * 128 + mi * 16 + quad * 4 + r;
            u16 sv = f2bf(silu_fast(acc[mi][ni][r] + bias));
            int g = ml >> 3, o = ml & 7;
            lds[nl * 256 + ((g ^ (nl & 7)) << 3) + o] = sv;
          }
      }
      __syncthreads();
      int row = t >> 1;  // e-row 0..255, two threads per row
      u16* o1p = (u16*)o1;
      size_t gbase = ((size_t)bb * E_ + nv0 + row) * T_ + tt0;
#pragma unroll
      for (int cc = 0; cc < 16; ++cc) {
        int c = (t & 1) * 16 + cc;
        int gs = c ^ (row & 7);
        uint4 val = *(const uint4*)&lds[row * 256 + gs * 8];
        *(uint4*)&o1p[gbase + c * 8] = val;
      }
    }
  } else if constexpr (MODE == 2) {
    // attn = (kernel @ v) * u, IN PLACE over u: LDS repack of bf16(acc),
    // then wide u-load * acc -> wide store.
#pragma unroll
    for (int ni = 0; ni < 4; ++ni) {
      int nl = wn * 64 + ni * 16 + l16;
      int g = nl >> 3, o = nl & 7;
#pragma unroll
      for (int mi = 0; mi < 8; ++mi)
#pragma unroll
        for (int r = 0; r < 4; ++r) {
          int ml = wm * 128 + mi * 16 + quad * 4 + r;
          lds[ml * 256 + ((g ^ (ml & 7)) << 3) + o] = f2bf(acc[mi][ni][r]);
        }
    }
    __syncthreads();
    const u16* uu = (const u16*)c0;
    u16* o0p = (u16*)o0;
#pragma unroll
    for (int cc = 0; cc < 16; ++cc) {
      int gidx = cc * 512 + t;
      int row = gidx >> 5, gc = gidx & 31;
      union { uint4 v; u16 h[8]; } av, uv_, rv;
      av.v = *(const uint4*)&lds[row * 256 + ((gc ^ (row & 7)) << 3)];
      size_t gi = ((size_t)z * T_ + m0 + row) * E_ + n0 + gc * 8;
      uv_.v = *(const uint4*)&uu[gi];
#pragma unroll
      for (int k = 0; k < 8; ++k)
        rv.h[k] = f2bf(bf2f(av.h[k]) * bf2f(uv_.h[k]));
      *(uint4*)&o0p[gi] = rv.v;
    }
  } else {
    // MODE 3: out = acc + o_b + shortcut -> f32 (full sectors; fine)
    const float* ob = (const float*)c0;
    const float* xs = (const float*)c1;
#pragma unroll
    for (int ni = 0; ni < 4; ++ni) {
      int n = n0 + wn * 64 + ni * 16 + l16;
      float bias = ob[n];
#pragma unroll
      for (int mi = 0; mi < 8; ++mi)
#pragma unroll
        for (int r = 0; r < 4; ++r) {
          int m = m0 + wm * 128 + mi * 16 + quad * 4 + r;
          size_t gi = (size_t)m * H_ + n;
          ((float*)o0)[gi] = acc[mi][ni][r] + bias + xs[gi];
        }
    }
  }
}

extern "C" void kernel_launch(void* const* d_in, const int* in_sizes, int n_in,
                              void* d_out, int out_size, void* d_ws, size_t ws_size,
                              hipStream_t stream) {
  const float* x     = (const float*)d_in[0];
  const float* ln_w  = (const float*)d_in[1];
  const float* ln_b  = (const float*)d_in[2];
  const float* uv_w  = (const float*)d_in[3];
  const float* uv_b  = (const float*)d_in[4];
  const float* gamma = (const float*)d_in[5];
  const float* beta  = (const float*)d_in[6];
  const float* wrel  = (const float*)d_in[7];
  const float* o_w   = (const float*)d_in[8];
  const float* o_b   = (const float*)d_in[9];

  char* ws = (char*)d_ws;
  u16*   xn   = (u16*)(ws);
  u16*   qb   = (u16*)(ws);
  u16*   kb   = (u16*)(ws + 4194304);
  u16*   km   = (u16*)(ws + 8388608);
  u16*   uvwb = (u16*)(ws + 33554432);
  u16*   owb  = (u16*)(ws + 42205184);
  u16*   u    = (u16*)(ws + 46399488);
  u16*   vt   = (u16*)(ws + 113508352);
  float* base = (float*)(ws + 180617216);
  u16*   attn = u;

  // one-time: allow 128 KiB dynamic LDS for the 256^2 kernels.
  static int ldsset = -1;
  if (ldsset < 0) {
    auto* k0 = gemm256<0, true>;
    auto* k2 = gemm256<2, false>;
    auto* k3 = gemm256<3, true>;
    hipFuncSetAttribute((const void*)k0, hipFuncAttributeMaxDynamicSharedMemorySize, 131072);
    hipFuncSetAttribute((const void*)k2, hipFuncAttributeMaxDynamicSharedMemorySize, 131072);
    hipFuncSetAttribute((const void*)k3, hipFuncAttributeMaxDynamicSharedMemorySize, 131072);
    ldsset = 1;
  }

  // 1. LayerNorm -> bf16
  ln_kernel<<<16384, 256, 0, stream>>>(x, ln_w, ln_b, xn);
  // 2. weight conversions
  cvt_kernel<<<4224, 256, 0, stream>>>(uv_w, uvwb, 4224 * 1024 / 4);
  cvt_kernel<<<2048, 256, 0, stream>>>(o_w, owb, 1024 * 2048 / 4);

  // 3a. uv GEMM, u+v columns (N=4096): 256^2 kernel
  gemm256<0, true><<<dim3(16, 64, 1), 512, 131072, stream>>>(
      xn, uvwb, 1024, 0, 0, u, vt, uv_b, nullptr);
  // 3b. base columns (4096..4223): legacy kernel, n-offset 4096 -> f32 base
  gemm_bt<0><<<dim3(1, 128, 1), 256, 0, stream>>>(
      xn, uvwb, 1024, 0, 0, nullptr, nullptr, base, uv_b, nullptr, 4096);
  // 4. gamma/beta + RoPE -> q,k (xn dead; qb/kb alias it)
  rope_kernel<<<4096, 256, 0, stream>>>(base, gamma, beta, qb, kb);
  // 5. qk per batch (K=128, tiny): legacy kernel
  gemm_bt<1><<<dim3(4, 4, 32), 256, 0, stream>>>(
      qb, kb, 128, 65536, 65536, km, nullptr, nullptr, wrel, nullptr, 0);
  // 6. kernel @ v per batch, * u in place
  gemm256<2, false><<<dim3(8, 2, 32), 512, 131072, stream>>>(
      km, vt, 512, 262144, 1048576, attn, nullptr, u, nullptr);
  // 7. final: + o_b + shortcut
  gemm256<3, true><<<dim3(4, 64, 1), 512, 131072, stream>>>(
      attn, owb, 2048, 0, 0, d_out, nullptr, o_b, x);
}